// Round 7
// baseline (190.346 us; speedup 1.0000x reference)
//
#include <hip/hip_runtime.h>
#include <stdint.h>

// Gemma4PatchEmbed round 14: HAND-SCHEDULED pipeline (asm loads + counted
// vmcnt). r13 evidence: VGPR_Count=64 while the depth-3 design needs ~110
// live regs -> compiler sank all loads to their uses, collapsing the
// software pipeline (dur unchanged 72us, 77% stall, MfmaUtil 10%).
// Fix (T3/T4 recipe): loads are asm volatile global_load_dwordx4 with
// SGPR-base + per-lane voffset addressing (k16-varying math on the scalar
// pipe), consumption gated by s_waitcnt vmcnt(10) -- never drained in-loop,
// 15 loads (3 slots x 5) in flight -- each wait followed by
// sched_barrier(0) (rule #18: stops MFMA hoisting past asm waits).
// Tripwires: VGPR still 64 => constraint failed; WRITE_SIZE >> 49MB => spill.
// Design otherwise unchanged: barrier-free, zero-LDS; A fragments
// (row=lane&31, k=(lane>>5)*8+j) = 8 consecutive floats of one pixel row
// read straight from global; fragment-linear bf16 B from bpack; cvt_pk
// convert; fused pos-gather epilogue.

typedef __attribute__((ext_vector_type(8))) short bfrag_t;         // MFMA A/B operand
typedef __attribute__((ext_vector_type(16))) float f16acc;          // 32x32 MFMA C/D
typedef __attribute__((ext_vector_type(8))) unsigned short u16x8;
typedef __attribute__((ext_vector_type(4))) float f32x4;            // native, no ctors
typedef __attribute__((ext_vector_type(4))) unsigned int u32x4;

#define V_POS 10240

__device__ __forceinline__ unsigned short f2bf(float f) {
    unsigned int u = __float_as_uint(f);
    u += 0x7fffu + ((u >> 16) & 1u);          // RNE fp32 -> bf16
    return (unsigned short)(u >> 16);
}

// ---------------------------------------------------------------------------
// Kernel 1: pack w_proj into fragment-linear bf16.
// chunk (n32, k16) = 1024 B; lane holds w_proj[n32*32 + (lane&31)]
// [k16*16 + (lane>>5)*8 + j], j<8. 288 blocks x 256 thr.
// ---------------------------------------------------------------------------
__global__ __launch_bounds__(256) void bpack_kernel(
    const float* __restrict__ wp, unsigned short* __restrict__ Bp)
{
    int u     = blockIdx.x * 256 + threadIdx.x;   // 0..73727
    int chunk = u >> 6;                           // 0..1151
    int lane  = u & 63;
    int n32   = chunk / 48;
    int k16   = chunk - n32 * 48;
    int n     = (n32 << 5) + (lane & 31);
    int k     = (k16 << 4) + ((lane >> 5) << 3);
    const float* s = wp + (size_t)n * 768 + k;
    f32x4 v0 = *(const f32x4*)s;
    f32x4 v1 = *(const f32x4*)(s + 4);
    u16x8 o;
    o[0] = f2bf(v0[0]); o[1] = f2bf(v0[1]); o[2] = f2bf(v0[2]); o[3] = f2bf(v0[3]);
    o[4] = f2bf(v1[0]); o[5] = f2bf(v1[1]); o[6] = f2bf(v1[2]); o[7] = f2bf(v1[3]);
    *(u16x8*)(Bp + (size_t)chunk * 512 + (lane << 3)) = o;
}

// ---------------------------------------------------------------------------
// Kernel 2: fused patch-extract + GEMM + pos-embed. 512 blocks x 512 threads.
// Block = 32 patch rows (one image patch-row) x 768 N; wave w owns cols
// w*96..w*96+95. Zero LDS, zero barriers, hand-counted vmcnt pipeline.
// ---------------------------------------------------------------------------
__global__ __launch_bounds__(512, 4) void fused_kernel(
    const float* __restrict__ px, const unsigned short* __restrict__ Bp,
    const int* __restrict__ pos_ids, const unsigned int* __restrict__ pad_in,
    const float* __restrict__ pos_table, float* __restrict__ out)
{
    const int tid  = threadIdx.x;
    const int wave = tid >> 6;                // 0..7
    const int lane = tid & 63;
    const int bid  = blockIdx.x;
    const int m0   = bid << 5;                // 32 patch rows per block
    const int img  = bid >> 5;
    const int prow = bid & 31;                // image pixel rows 16*prow .. +16

    // padding-bool upload-width probe FIRST (its vmem load must retire
    // before/among the prologue; wait(10) analysis tolerates one extra).
    const bool u8mode = __any(pad_in[lane] > 1u);

    // Uniform (SGPR) byte bases; per-lane (VGPR) static offsets.
    const uint64_t pxu = (uint64_t)px + (uint64_t)img * 3145728u
                       + (uint64_t)prow * 32768u;          // image + row strip
    const uint64_t Bpu = (uint64_t)Bp;
    const unsigned int voffA =
        (((lane & 31) << 4) + ((lane >> 5) << 3)) << 2;    // col8 * 4 B
    const unsigned int voffB = wave * 147456u + (lane << 4); // frag base, bytes

    f16acc acc[3] = {};

    // depth-3 circular pipeline: named slots, all-static register use
    f32x4   a0r0, a0r1, a1r0, a1r1, a2r0, a2r1;   // raw fp32 A staging
    bfrag_t b00, b01, b02, b10, b11, b12, b20, b21, b22;

// issue one slot's 5 loads: A = 2 x dwordx4 (SGPR base = channel/row of k16,
// +16B imm for second half), B = 3 x dwordx4 (SGPR base = Bp + k16*1KB,
// columns +48KB/+96KB via scalar adds).
#define LOADSLOT(kn, ar0, ar1, bb0, bb1, bb2) do {                            \
    uint64_t uA_ = pxu + (uint64_t)((((kn) >> 4) << 20) + (((kn) & 15) << 11)); \
    uint64_t uB_ = Bpu + ((uint64_t)(kn) << 10);                              \
    asm volatile("global_load_dwordx4 %0, %2, %3\n\t"                         \
                 "global_load_dwordx4 %1, %2, %3 offset:16"                   \
                 : "=&v"(ar0), "=&v"(ar1) : "v"(voffA), "s"(uA_));            \
    asm volatile("global_load_dwordx4 %0, %1, %2"                             \
                 : "=&v"(bb0) : "v"(voffB), "s"(uB_));                        \
    asm volatile("global_load_dwordx4 %0, %1, %2"                             \
                 : "=&v"(bb1) : "v"(voffB), "s"(uB_ + 49152u));               \
    asm volatile("global_load_dwordx4 %0, %1, %2"                             \
                 : "=&v"(bb2) : "v"(voffB), "s"(uB_ + 98304u));               \
} while (0)

#define WAITV(N) do {                                                         \
    asm volatile("s_waitcnt vmcnt(" #N ")" ::: "memory");                     \
    __builtin_amdgcn_sched_barrier(0);                                        \
} while (0)

#define CVTPK(lo, hi, d) asm("v_cvt_pk_bf16_f32 %0, %1, %2"                   \
        : "=v"(d) : "v"(lo), "v"(hi))
#define CVT(r0, r1, dst) {                                                    \
        unsigned int p0_, p1_, p2_, p3_;                                      \
        CVTPK(fmaf(2.f, r0[0], -1.f), fmaf(2.f, r0[1], -1.f), p0_);           \
        CVTPK(fmaf(2.f, r0[2], -1.f), fmaf(2.f, r0[3], -1.f), p1_);           \
        CVTPK(fmaf(2.f, r1[0], -1.f), fmaf(2.f, r1[1], -1.f), p2_);           \
        CVTPK(fmaf(2.f, r1[2], -1.f), fmaf(2.f, r1[3], -1.f), p3_);           \
        u32x4 pk_ = {p0_, p1_, p2_, p3_};                                     \
        dst = __builtin_bit_cast(bfrag_t, pk_); }
#define MFMA3(a0, b0, b1, b2)                                                 \
        acc[0] = __builtin_amdgcn_mfma_f32_32x32x16_bf16(a0, b0, acc[0], 0, 0, 0); \
        acc[1] = __builtin_amdgcn_mfma_f32_32x32x16_bf16(a0, b1, acc[1], 0, 0, 0); \
        acc[2] = __builtin_amdgcn_mfma_f32_32x32x16_bf16(a0, b2, acc[2], 0, 0, 0);

// steady-state slot: wait until this slot's 5 loads done (10 newer stay in
// flight), consume (CVT+MFMA), refill slot with k16=kn.
#define STEP(kn, ar0, ar1, bb0, bb1, bb2) do {                                \
    WAITV(10);                                                                \
    bfrag_t a_f; CVT(ar0, ar1, a_f);                                          \
    MFMA3(a_f, bb0, bb1, bb2);                                                \
    LOADSLOT(kn, ar0, ar1, bb0, bb1, bb2);                                    \
} while (0)
#define STEPT(W, ar0, ar1, bb0, bb1, bb2) do {                                \
    WAITV(W);                                                                 \
    bfrag_t a_f; CVT(ar0, ar1, a_f);                                          \
    MFMA3(a_f, bb0, bb1, bb2);                                                \
} while (0)

    LOADSLOT(0, a0r0, a0r1, b00, b01, b02);   // prologue: k16 = 0,1,2
    LOADSLOT(1, a1r0, a1r1, b10, b11, b12);
    LOADSLOT(2, a2r0, a2r1, b20, b21, b22);

    // 15 iterations: consume k16..k16+2, refill k16+3..k16+5 (last = 45,46,47)
    for (int k16 = 0; k16 < 45; k16 += 3) {
        STEP(k16 + 3, a0r0, a0r1, b00, b01, b02);
        STEP(k16 + 4, a1r0, a1r1, b10, b11, b12);
        STEP(k16 + 5, a2r0, a2r1, b20, b21, b22);
    }
    STEPT(10, a0r0, a0r1, b00, b01, b02);     // k16 = 45
    STEPT(5,  a1r0, a1r1, b10, b11, b12);     // k16 = 46
    STEPT(0,  a2r0, a2r1, b20, b21, b22);     // k16 = 47
#undef LOADSLOT
#undef WAITV
#undef CVTPK
#undef CVT
#undef MFMA3
#undef STEP
#undef STEPT

    // ---- epilogue: 32x32 C/D layout col=lane&31, row=(r&3)+8*(r>>2)+4*(lane>>5)
    const unsigned char* pad8 = (const unsigned char*)pad_in;
    const int cl  = lane & 31;
    const int h4  = (lane >> 5) << 2;
#pragma unroll
    for (int r = 0; r < 16; ++r) {
        int row = (r & 3) + ((r >> 2) << 3) + h4;
        int gm  = m0 + row;
        int xid = pos_ids[2 * gm];
        int yid = pos_ids[2 * gm + 1];
        xid = xid < 0 ? 0 : xid;
        yid = yid < 0 ? 0 : yid;
        bool p = u8mode ? (pad8[gm] != 0) : (pad_in[gm] != 0u);
        const float* t0 = pos_table + (size_t)xid * 768;
        const float* t1 = pos_table + (size_t)(V_POS + yid) * 768;
        float* orow = out + (size_t)gm * 768;
#pragma unroll
        for (int nt = 0; nt < 3; ++nt) {
            int col = wave * 96 + (nt << 5) + cl;
            float pos = p ? 0.f : (t0[col] + t1[col]);
            orow[col] = acc[nt][r] + pos;
        }
    }
}

extern "C" void kernel_launch(void* const* d_in, const int* in_sizes, int n_in,
                              void* d_out, int out_size, void* d_ws, size_t ws_size,
                              hipStream_t stream) {
    const float*        px  = (const float*)d_in[0];        // (16,3,512,512)
    const float*        wp  = (const float*)d_in[1];        // (768,768)
    const float*        pt  = (const float*)d_in[2];        // (2,10240,768)
    const int*          pid = (const int*)d_in[3];          // (16,1024,2)
    const unsigned int* pad = (const unsigned int*)d_in[4]; // (16,1024) bool

    unsigned short* Bp = (unsigned short*)d_ws;             // 1.18 MB packed bf16

    bpack_kernel<<<288, 256, 0, stream>>>(wp, Bp);
    fused_kernel<<<512, 512, 0, stream>>>(px, Bp, pid, pad, pt, (float*)d_out);
}